// Round 5
// baseline (183.494 us; speedup 1.0000x reference)
//
#include <hip/hip_runtime.h>
#include <math.h>

// N=4096 nodes, D=256, S=32, K=4 heads, ETA=0.5.
// adj_mask is binary {0,1} (~2% density + self-loops): masked softmax ==
// exact sparse softmax over each row's neighbor set (exp(-1e9-max)==0 in fp32).
constexpr int NN = 4096;
constexpr int DD = 256;
constexpr int SS = 32;
constexpr int KK = 4;
constexpr int MAXN = 192;    // row degree: mean 83, sd 9 -> 192 = +12 sd
constexpr int SEGMAX = 96;   // per-quarter-row degree: mean ~21, sd 4.5
constexpr float ETA = 0.5f;

#define MEMFENCE() __asm__ volatile("" ::: "memory")

// ---------------------------------------------------------------------------
// Kernel 1 (prep):
//   blocks [0,1024):  Z[k] = H @ U[k]; block b -> head k=b&3, nodes (b>>2)*16..+16
//   blocks [1024,1034): orth-loss partial for one (k<=l) pair -> lossp[pair];
//                       pair 0 also writes elp = exp(log_precision).
// ---------------------------------------------------------------------------
__global__ __launch_bounds__(256) void prep_kernel(
    const float* __restrict__ H, const float* __restrict__ U,
    const float* __restrict__ lp, float* __restrict__ Z,
    float* __restrict__ elp, float* __restrict__ lossp) {
  __shared__ float Hl[16][DD];   // 16 KB (Z path only)
  __shared__ float red[4];
  const int tid = threadIdx.x;

  if (blockIdx.x < 1024) {
    const int k = blockIdx.x & 3;
    const int n0 = (blockIdx.x >> 2) * 16;

    const float4* H4 = (const float4*)(H + (size_t)n0 * DD);
    float4* Hl4 = (float4*)&Hl[0][0];
    for (int i = tid; i < 16 * DD / 4; i += 256) Hl4[i] = H4[i];
    __syncthreads();

    const int s = tid & 31;
    const int n_l = (tid >> 5) & 7;   // 0..7; thread owns nodes n_l and n_l+8
    const float* Uk = U + (size_t)k * DD * SS;
    float acc0 = 0.f, acc1 = 0.f;
#pragma unroll 4
    for (int dq = 0; dq < DD / 4; dq++) {
      const float4 h0 = Hl4[n_l * (DD / 4) + dq];        // LDS broadcast b128
      const float4 h1 = Hl4[(n_l + 8) * (DD / 4) + dq];
      const float u0 = Uk[(4 * dq + 0) * SS + s];        // coalesced 128B
      const float u1 = Uk[(4 * dq + 1) * SS + s];
      const float u2 = Uk[(4 * dq + 2) * SS + s];
      const float u3 = Uk[(4 * dq + 3) * SS + s];
      acc0 += h0.x * u0 + h0.y * u1 + h0.z * u2 + h0.w * u3;
      acc1 += h1.x * u0 + h1.y * u1 + h1.z * u2 + h1.w * u3;
    }
    Z[((size_t)k * NN + n0 + n_l) * SS + s] = acc0;
    Z[((size_t)k * NN + n0 + n_l + 8) * SS + s] = acc1;
  } else {
    // ---- orth path: one (k<=l) pair per block ----
    const int pair = blockIdx.x - 1024;
    if (pair == 0 && tid < KK * SS) elp[tid] = expf(lp[tid]);
    const int pk[10] = {0, 0, 0, 0, 1, 1, 1, 2, 2, 3};
    const int pl[10] = {0, 1, 2, 3, 1, 2, 3, 2, 3, 3};
    const int k = pk[pair], l = pl[pair];
    const int b = tid & 31;
    const int a0 = tid >> 5;          // cell a = a0 + 8*j
    float acc[4] = {0.f, 0.f, 0.f, 0.f};
    for (int d = 0; d < DD; d++) {
      const float ub = U[((size_t)l * DD + d) * SS + b];
#pragma unroll
      for (int j = 0; j < 4; j++)
        acc[j] += U[((size_t)k * DD + d) * SS + a0 + 8 * j] * ub;
    }
    float tot = 0.f;
#pragma unroll
    for (int j = 0; j < 4; j++) {
      const float cv = acc[j] - ((k == l && (a0 + 8 * j) == b) ? 1.0f : 0.0f);
      tot += cv * cv;
    }
#pragma unroll
    for (int off = 32; off >= 1; off >>= 1) tot += __shfl_xor(tot, off);
    if ((tid & 63) == 0) red[tid >> 6] = tot;
    __syncthreads();
    if (tid == 0) lossp[pair] = red[0] + red[1] + red[2] + red[3];
  }
}

// ---------------------------------------------------------------------------
// Kernel 2: one ROW per block, one HEAD per wave (4 waves).
//   Scan: each wave ballot-compacts its quarter of the mask row (4 iters).
//   Merge: prefix over 4 segment counts -> packed nbr[] list.
//   Attention (wave k): lane holds neighbors p=lane and p=lane+64 ENTIRELY in
//   registers (rare 3rd at lane+128 via uniform branch + reload). Dots are
//   lane-local; single wave max + single wave sum; PV partial lane-local;
//   multi-value butterfly (31 shuffles) reduces 64x32 partials -> lane 2m
//   holds O[m]; even lanes store straight to global AO.
// ---------------------------------------------------------------------------
__global__ __launch_bounds__(256) void attn_row(
    const float* __restrict__ mask, const float* __restrict__ Z,
    const float* __restrict__ elp, const float* __restrict__ lossp,
    float* __restrict__ AO, float* __restrict__ loss) {
  const int tid = threadIdx.x;
  const int wv = tid >> 6;
  const int lane = tid & 63;
  const int row = blockIdx.x;

  __shared__ int segn[4][SEGMAX];
  __shared__ int segc[4];
  __shared__ int nbr[MAXN];

  if (blockIdx.x == 0 && tid == 0) {
    float t = 0.f;
#pragma unroll
    for (int i = 0; i < 10; i++) t += lossp[i];
    loss[0] = t;
  }

  // --- scan: wave wv covers float4 indices [wv*256, wv*256+256) of the row ---
  const float4* m4 = (const float4*)(mask + (size_t)row * NN);
  const unsigned long long lt = (1ULL << lane) - 1ULL;
  int cnt = 0;
#pragma unroll
  for (int it = 0; it < 4; it++) {
    const int i = wv * 256 + it * 64 + lane;   // coalesced within wave
    const float4 v = m4[i];
    unsigned long long b;
    b = __ballot(v.x > 0.5f);
    if (v.x > 0.5f) { const int p = cnt + (int)__popcll(b & lt); if (p < SEGMAX) segn[wv][p] = 4 * i; }
    cnt += (int)__popcll(b);
    b = __ballot(v.y > 0.5f);
    if (v.y > 0.5f) { const int p = cnt + (int)__popcll(b & lt); if (p < SEGMAX) segn[wv][p] = 4 * i + 1; }
    cnt += (int)__popcll(b);
    b = __ballot(v.z > 0.5f);
    if (v.z > 0.5f) { const int p = cnt + (int)__popcll(b & lt); if (p < SEGMAX) segn[wv][p] = 4 * i + 2; }
    cnt += (int)__popcll(b);
    b = __ballot(v.w > 0.5f);
    if (v.w > 0.5f) { const int p = cnt + (int)__popcll(b & lt); if (p < SEGMAX) segn[wv][p] = 4 * i + 3; }
    cnt += (int)__popcll(b);
  }
  if (lane == 0) segc[wv] = min(cnt, SEGMAX);
  MEMFENCE();
  __syncthreads();

  // --- merge segments into packed nbr[] ---
  const int c0 = segc[0], c1 = segc[1], c2 = segc[2], c3 = segc[3];
  const int offs[4] = {0, c0, c0 + c1, c0 + c1 + c2};
  const int c = min(c0 + c1 + c2 + c3, MAXN);
  const int myc = segc[wv];
  const int myoff = offs[wv];
  for (int i = lane; i < myc; i += 64) {
    const int p = myoff + i;
    if (p < MAXN) nbr[p] = segn[wv][i];
  }
  MEMFENCE();
  __syncthreads();

  // --- head k = wv ---
  const int k = wv;
  const float inv_sqrt_s = 0.17677669529663687f;  // 1/sqrt(32)
  const float* Zk = Z + (size_t)k * NN * SS;

  // full precision-scaled query row in registers (broadcast loads)
  const float4* Zq4 = (const float4*)(Z + ((size_t)k * NN + row) * SS);
  const float4* E4 = (const float4*)(elp + k * SS);
  float q[SS];
#pragma unroll
  for (int u = 0; u < 8; u++) {
    const float4 a = Zq4[u], e = E4[u];
    q[4 * u + 0] = a.x * e.x; q[4 * u + 1] = a.y * e.y;
    q[4 * u + 2] = a.z * e.z; q[4 * u + 3] = a.w * e.w;
  }

  // two resident neighbors per lane, rows fully in registers
  const int pA = lane, pB = lane + 64;
  const bool aA = pA < c, aB = pB < c;
  float zA[SS], zB[SS];
  if (aA) {
    const float4* r = (const float4*)(Zk + (size_t)nbr[pA] * SS);
#pragma unroll
    for (int u = 0; u < 8; u++) {
      const float4 v = r[u];
      zA[4 * u] = v.x; zA[4 * u + 1] = v.y; zA[4 * u + 2] = v.z; zA[4 * u + 3] = v.w;
    }
  } else {
#pragma unroll
    for (int i = 0; i < SS; i++) zA[i] = 0.f;
  }
  if (aB) {
    const float4* r = (const float4*)(Zk + (size_t)nbr[pB] * SS);
#pragma unroll
    for (int u = 0; u < 8; u++) {
      const float4 v = r[u];
      zB[4 * u] = v.x; zB[4 * u + 1] = v.y; zB[4 * u + 2] = v.z; zB[4 * u + 3] = v.w;
    }
  } else {
#pragma unroll
    for (int i = 0; i < SS; i++) zB[i] = 0.f;
  }

  // lane-local dots (no shuffles)
  float sA = -3.0e38f, sB = -3.0e38f, sC = -3.0e38f;
  {
    float dA = 0.f, dB = 0.f;
#pragma unroll
    for (int i = 0; i < SS; i++) { dA += q[i] * zA[i]; dB += q[i] * zB[i]; }
    if (aA) sA = dA * inv_sqrt_s;
    if (aB) sB = dB * inv_sqrt_s;
  }
  // rare 3rd neighbor: score-only pass (row reloaded later for PV)
  const bool has3 = (c > 128);
  if (has3) {
    const int pC = lane + 128;
    if (pC < c) {
      const float4* r = (const float4*)(Zk + (size_t)nbr[pC] * SS);
      float d = 0.f;
#pragma unroll
      for (int u = 0; u < 8; u++) {
        const float4 v = r[u];
        d += q[4 * u] * v.x + q[4 * u + 1] * v.y + q[4 * u + 2] * v.z + q[4 * u + 3] * v.w;
      }
      sC = d * inv_sqrt_s;
    }
  }

  // single wave max + single wave sum
  float mx = fmaxf(sA, fmaxf(sB, sC));
#pragma unroll
  for (int off = 32; off >= 1; off >>= 1) mx = fmaxf(mx, __shfl_xor(mx, off));
  const float wA = __expf(sA - mx);   // inactive -> exp(-huge) = 0
  const float wB = __expf(sB - mx);
  const float wC = __expf(sC - mx);
  float sv = wA + wB + wC;
#pragma unroll
  for (int off = 32; off >= 1; off >>= 1) sv += __shfl_xor(sv, off);
  const float invl = 1.0f / sv;       // c >= 1 (self-loop) -> sv > 0

  // lane-local PV partials
  float o[SS];
#pragma unroll
  for (int i = 0; i < SS; i++) o[i] = wA * zA[i] + wB * zB[i];
  if (has3) {
    const int pC = lane + 128;
    if (pC < c) {
      const float4* r = (const float4*)(Zk + (size_t)nbr[pC] * SS);
#pragma unroll
      for (int u = 0; u < 8; u++) {
        const float4 v = r[u];
        o[4 * u] += wC * v.x; o[4 * u + 1] += wC * v.y;
        o[4 * u + 2] += wC * v.z; o[4 * u + 3] += wC * v.w;
      }
    }
  }

  // multi-value butterfly: 64 lanes x 32 values -> lane pair 2m holds O[m].
  // Stage X: exchange live half; lane bit log2(X) selects kept index half.
#pragma unroll
  for (int i = 0; i < 16; i++) {
    const float snd = (lane & 32) ? o[i] : o[i + 16];
    const float rcv = __shfl_xor(snd, 32);
    o[i] = ((lane & 32) ? o[i + 16] : o[i]) + rcv;
  }
#pragma unroll
  for (int i = 0; i < 8; i++) {
    const float snd = (lane & 16) ? o[i] : o[i + 8];
    const float rcv = __shfl_xor(snd, 16);
    o[i] = ((lane & 16) ? o[i + 8] : o[i]) + rcv;
  }
#pragma unroll
  for (int i = 0; i < 4; i++) {
    const float snd = (lane & 8) ? o[i] : o[i + 4];
    const float rcv = __shfl_xor(snd, 8);
    o[i] = ((lane & 8) ? o[i + 4] : o[i]) + rcv;
  }
#pragma unroll
  for (int i = 0; i < 2; i++) {
    const float snd = (lane & 4) ? o[i] : o[i + 2];
    const float rcv = __shfl_xor(snd, 4);
    o[i] = ((lane & 4) ? o[i + 2] : o[i]) + rcv;
  }
  {
    const float snd = (lane & 2) ? o[0] : o[1];
    const float rcv = __shfl_xor(snd, 2);
    o[0] = ((lane & 2) ? o[1] : o[0]) + rcv;
  }
  const float ofin = o[0] + __shfl_xor(o[0], 1);  // dim = lane >> 1

  if ((lane & 1) == 0)
    AO[(size_t)row * (KK * SS) + k * SS + (lane >> 1)] = ofin * invl;
}

// ---------------------------------------------------------------------------
// Kernel 3 (epilogue): Hout = softthresh(H + ETA * AO @ Ufl), Ufl[(k,s)][d]=U[k][d][s].
// 4 rows per block, 1024 blocks; d = tid; AO tile staged in LDS.
// ---------------------------------------------------------------------------
__global__ __launch_bounds__(256) void epilogue_kernel(
    const float* __restrict__ H, const float* __restrict__ U,
    const float* __restrict__ thr, const float* __restrict__ AO,
    float* __restrict__ Hout) {
  __shared__ float AOl[4][KK * SS];   // 2 KB
  const int tid = threadIdx.x;
  const int r0 = blockIdx.x * 4;

  const float4* AO4 = (const float4*)(AO + (size_t)r0 * KK * SS);
  float4* AOl4 = (float4*)&AOl[0][0];
  if (tid < 128) AOl4[tid] = AO4[tid];
  __syncthreads();

  const int d = tid;
  float acc[4] = {0.f, 0.f, 0.f, 0.f};
  const float4* U4 = (const float4*)U;
#pragma unroll
  for (int k = 0; k < KK; k++) {
    const int ubase = (k * DD + d) * (SS / 4);
#pragma unroll
    for (int sq = 0; sq < SS / 4; sq++) {
      const float4 u = U4[ubase + sq];   // thread's 128B row of U[k][d][:]
#pragma unroll
      for (int r = 0; r < 4; r++) {
        const float4 a = AOl4[r * (KK * SS / 4) + k * (SS / 4) + sq];  // LDS b128 broadcast
        acc[r] += u.x * a.x + u.y * a.y + u.z * a.z + u.w * a.w;
      }
    }
  }
  const float tv = thr[d];
#pragma unroll
  for (int r = 0; r < 4; r++) {
    const float h = H[(size_t)(r0 + r) * DD + d] + ETA * acc[r];
    const float ab = fabsf(h) - tv;
    Hout[(size_t)(r0 + r) * DD + d] = (ab > 0.0f) ? copysignf(ab, h) : 0.0f;
  }
}

// ---------------------------------------------------------------------------
extern "C" void kernel_launch(void* const* d_in, const int* in_sizes, int n_in,
                              void* d_out, int out_size, void* d_ws, size_t ws_size,
                              hipStream_t stream) {
  const float* H    = (const float*)d_in[0];
  const float* mask = (const float*)d_in[1];
  const float* U    = (const float*)d_in[2];
  const float* lp   = (const float*)d_in[3];
  const float* thr  = (const float*)d_in[4];

  float* Hout = (float*)d_out;
  float* loss = Hout + (size_t)NN * DD;      // outputs: [N*D] + [1]

  float* Z     = (float*)d_ws;               // [K][N][S]   2 MB (16B aligned)
  float* AO    = Z + (size_t)KK * NN * SS;   // [N][K*S]    2 MB (16B aligned)
  float* elp   = AO + (size_t)NN * KK * SS;  // [K*S]       (16B aligned)
  float* lossp = elp + KK * SS;              // [10]

  prep_kernel<<<1034, 256, 0, stream>>>(H, U, lp, Z, elp, lossp);
  attn_row<<<NN, 256, 0, stream>>>(mask, Z, elp, lossp, AO, loss);
  epilogue_kernel<<<NN / 4, 256, 0, stream>>>(H, U, thr, AO, Hout);
}

// Round 6
// 164.427 us; speedup vs baseline: 1.1160x; 1.1160x over previous
//
#include <hip/hip_runtime.h>
#include <math.h>

// N=4096 nodes, D=256, S=32, K=4 heads, ETA=0.5.
// adj_mask is binary {0,1} (~2% density + self-loops): masked softmax ==
// exact sparse softmax over each row's neighbor set (exp(-1e9-max)==0 in fp32).
constexpr int NN = 4096;
constexpr int DD = 256;
constexpr int SS = 32;
constexpr int KK = 4;
constexpr int MAXN = 192;    // row degree: mean 83, sd 9 -> 192 = +12 sd
constexpr int SEGMAX = 96;   // per-quarter-row degree: mean ~21, sd 4.5
constexpr float ETA = 0.5f;

#define MEMFENCE() __asm__ volatile("" ::: "memory")

// ---------------------------------------------------------------------------
// Kernel 1 (prep):
//   blocks [0,1024):  Z[k] = H @ U[k]; block b -> head k=b&3, nodes (b>>2)*16..+16
//   blocks [1024,1034): orth-loss partial for one (k<=l) pair -> lossp[pair];
//                       pair 0 also writes elp = exp(log_precision).
// ---------------------------------------------------------------------------
__global__ __launch_bounds__(256) void prep_kernel(
    const float* __restrict__ H, const float* __restrict__ U,
    const float* __restrict__ lp, float* __restrict__ Z,
    float* __restrict__ elp, float* __restrict__ lossp) {
  __shared__ float Hl[16][DD];   // 16 KB (Z path only)
  __shared__ float red[4];
  const int tid = threadIdx.x;

  if (blockIdx.x < 1024) {
    const int k = blockIdx.x & 3;
    const int n0 = (blockIdx.x >> 2) * 16;

    const float4* H4 = (const float4*)(H + (size_t)n0 * DD);
    float4* Hl4 = (float4*)&Hl[0][0];
    for (int i = tid; i < 16 * DD / 4; i += 256) Hl4[i] = H4[i];
    __syncthreads();

    const int s = tid & 31;
    const int n_l = (tid >> 5) & 7;   // 0..7; thread owns nodes n_l and n_l+8
    const float* Uk = U + (size_t)k * DD * SS;
    float acc0 = 0.f, acc1 = 0.f;
#pragma unroll 4
    for (int dq = 0; dq < DD / 4; dq++) {
      const float4 h0 = Hl4[n_l * (DD / 4) + dq];        // LDS broadcast b128
      const float4 h1 = Hl4[(n_l + 8) * (DD / 4) + dq];
      const float u0 = Uk[(4 * dq + 0) * SS + s];        // coalesced 128B
      const float u1 = Uk[(4 * dq + 1) * SS + s];
      const float u2 = Uk[(4 * dq + 2) * SS + s];
      const float u3 = Uk[(4 * dq + 3) * SS + s];
      acc0 += h0.x * u0 + h0.y * u1 + h0.z * u2 + h0.w * u3;
      acc1 += h1.x * u0 + h1.y * u1 + h1.z * u2 + h1.w * u3;
    }
    Z[((size_t)k * NN + n0 + n_l) * SS + s] = acc0;
    Z[((size_t)k * NN + n0 + n_l + 8) * SS + s] = acc1;
  } else {
    // ---- orth path: one (k<=l) pair per block ----
    const int pair = blockIdx.x - 1024;
    if (pair == 0 && tid < KK * SS) elp[tid] = expf(lp[tid]);
    const int pk[10] = {0, 0, 0, 0, 1, 1, 1, 2, 2, 3};
    const int pl[10] = {0, 1, 2, 3, 1, 2, 3, 2, 3, 3};
    const int k = pk[pair], l = pl[pair];
    const int b = tid & 31;
    const int a0 = tid >> 5;          // cell a = a0 + 8*j
    float acc[4] = {0.f, 0.f, 0.f, 0.f};
    for (int d = 0; d < DD; d++) {
      const float ub = U[((size_t)l * DD + d) * SS + b];
#pragma unroll
      for (int j = 0; j < 4; j++)
        acc[j] += U[((size_t)k * DD + d) * SS + a0 + 8 * j] * ub;
    }
    float tot = 0.f;
#pragma unroll
    for (int j = 0; j < 4; j++) {
      const float cv = acc[j] - ((k == l && (a0 + 8 * j) == b) ? 1.0f : 0.0f);
      tot += cv * cv;
    }
#pragma unroll
    for (int off = 32; off >= 1; off >>= 1) tot += __shfl_xor(tot, off);
    if ((tid & 63) == 0) red[tid >> 6] = tot;
    __syncthreads();
    if (tid == 0) lossp[pair] = red[0] + red[1] + red[2] + red[3];
  }
}

// ---------------------------------------------------------------------------
// Kernel 2: one ROW per block, one HEAD per wave (4 waves).
//   Scan: each wave ballot-compacts its quarter of the mask row (4 iters).
//   Merge: prefix over 4 segment counts -> packed nbr[] list.
//   Head (wave k), TWO-PASS softmax with scores in per-wave LDS:
//     Pass 1: all score dots, chunk layout (p_sub in [0,8), sq in [0,8)),
//             iterations independent (loads pipeline); one wave max.
//     Pass 1.5: w = exp(sc - max) written back to LDS (3/lane); one wave sum.
//     Pass 2: o4 += w[p] * z4 (re-gather, L1/L2-hot, independent); one
//             12-shuffle reduce over p_sub; 128B coalesced store to AO.
//   No serial per-chunk softmax chain; VGPR stays low (~40).
// ---------------------------------------------------------------------------
__global__ __launch_bounds__(256) void attn_row(
    const float* __restrict__ mask, const float* __restrict__ Z,
    const float* __restrict__ elp, const float* __restrict__ lossp,
    float* __restrict__ AO, float* __restrict__ loss) {
  const int tid = threadIdx.x;
  const int wv = tid >> 6;
  const int lane = tid & 63;
  const int row = blockIdx.x;

  __shared__ int segn[4][SEGMAX];
  __shared__ int segc[4];
  __shared__ int nbr[MAXN];
  __shared__ float scw[4][MAXN];   // per-wave score/weight buffer (3 KB)

  if (blockIdx.x == 0 && tid == 0) {
    float t = 0.f;
#pragma unroll
    for (int i = 0; i < 10; i++) t += lossp[i];
    loss[0] = t;
  }

  // --- scan: wave wv covers float4 indices [wv*256, wv*256+256) of the row ---
  const float4* m4 = (const float4*)(mask + (size_t)row * NN);
  const unsigned long long lt = (1ULL << lane) - 1ULL;
  int cnt = 0;
#pragma unroll
  for (int it = 0; it < 4; it++) {
    const int i = wv * 256 + it * 64 + lane;   // coalesced within wave
    const float4 v = m4[i];
    unsigned long long b;
    b = __ballot(v.x > 0.5f);
    if (v.x > 0.5f) { const int p = cnt + (int)__popcll(b & lt); if (p < SEGMAX) segn[wv][p] = 4 * i; }
    cnt += (int)__popcll(b);
    b = __ballot(v.y > 0.5f);
    if (v.y > 0.5f) { const int p = cnt + (int)__popcll(b & lt); if (p < SEGMAX) segn[wv][p] = 4 * i + 1; }
    cnt += (int)__popcll(b);
    b = __ballot(v.z > 0.5f);
    if (v.z > 0.5f) { const int p = cnt + (int)__popcll(b & lt); if (p < SEGMAX) segn[wv][p] = 4 * i + 2; }
    cnt += (int)__popcll(b);
    b = __ballot(v.w > 0.5f);
    if (v.w > 0.5f) { const int p = cnt + (int)__popcll(b & lt); if (p < SEGMAX) segn[wv][p] = 4 * i + 3; }
    cnt += (int)__popcll(b);
  }
  if (lane == 0) segc[wv] = min(cnt, SEGMAX);
  MEMFENCE();
  __syncthreads();

  // --- merge segments into packed nbr[] ---
  const int c0 = segc[0], c1 = segc[1], c2 = segc[2], c3 = segc[3];
  const int offs[4] = {0, c0, c0 + c1, c0 + c1 + c2};
  const int c = min(c0 + c1 + c2 + c3, MAXN);
  const int myc = segc[wv];
  const int myoff = offs[wv];
  for (int i = lane; i < myc; i += 64) {
    const int p = myoff + i;
    if (p < MAXN) nbr[p] = segn[wv][i];
  }
  MEMFENCE();
  __syncthreads();

  // --- head k = wv ---
  const int k = wv;
  const int p_sub = lane >> 3;   // neighbor slot within chunk
  const int sq = lane & 7;       // float4 slice of the 32-dim row
  const float inv_sqrt_s = 0.17677669529663687f;  // 1/sqrt(32)
  const float* Zk = Z + (size_t)k * NN * SS;

  // query quad: q4 = Z[k][row][4sq..] * exp(lp[k][...])  (broadcast loads)
  float4 q4;
  {
    const float4 a = ((const float4*)(Z + ((size_t)k * NN + row) * SS))[sq];
    const float4 e = ((const float4*)(elp + k * SS))[sq];
    q4.x = a.x * e.x; q4.y = a.y * e.y; q4.z = a.z * e.z; q4.w = a.w * e.w;
  }

  // --- Pass 1: scores -> LDS; iterations independent (16 neighbors/iter) ---
  float lmax = -3.0e38f;
  for (int p0 = 0; p0 < c; p0 += 16) {
    const int pa = p0 + p_sub;
    const int pb = pa + 8;
    const bool aA = pa < c, aB = pb < c;
    float4 zA = {0.f, 0.f, 0.f, 0.f}, zB = {0.f, 0.f, 0.f, 0.f};
    if (aA) zA = ((const float4*)(Zk + (size_t)nbr[pa] * SS))[sq];
    if (aB) zB = ((const float4*)(Zk + (size_t)nbr[pb] * SS))[sq];
    float dA = q4.x * zA.x + q4.y * zA.y + q4.z * zA.z + q4.w * zA.w;
    float dB = q4.x * zB.x + q4.y * zB.y + q4.z * zB.z + q4.w * zB.w;
    dA += __shfl_xor(dA, 1); dB += __shfl_xor(dB, 1);
    dA += __shfl_xor(dA, 2); dB += __shfl_xor(dB, 2);
    dA += __shfl_xor(dA, 4); dB += __shfl_xor(dB, 4);
    dA = aA ? dA * inv_sqrt_s : -3.0e38f;
    dB = aB ? dB * inv_sqrt_s : -3.0e38f;
    if (sq == 0 && aA) scw[wv][pa] = dA;
    if (sq == 0 && aB) scw[wv][pb] = dB;
    lmax = fmaxf(lmax, fmaxf(dA, dB));
  }
  MEMFENCE();
#pragma unroll
  for (int off = 32; off >= 1; off >>= 1) lmax = fmaxf(lmax, __shfl_xor(lmax, off));

  // --- Pass 1.5: exponentiate in LDS, accumulate sum (3 exps/lane max) ---
  float wsum = 0.f;
#pragma unroll
  for (int t = 0; t < 3; t++) {
    const int p = lane + t * 64;
    if (p < c) {
      const float w = __expf(scw[wv][p] - lmax);
      scw[wv][p] = w;
      wsum += w;
    }
  }
  MEMFENCE();
#pragma unroll
  for (int off = 32; off >= 1; off >>= 1) wsum += __shfl_xor(wsum, off);
  const float invl = 1.0f / wsum;   // c >= 1 (self-loop) -> wsum > 0

  // --- Pass 2: weighted V-sum; re-gather z4 (L1/L2-hot), LDS-broadcast w ---
  float4 o4 = {0.f, 0.f, 0.f, 0.f};
  for (int p0 = 0; p0 < c; p0 += 16) {
    const int pa = p0 + p_sub;
    const int pb = pa + 8;
    const bool aA = pa < c, aB = pb < c;
    float wA = 0.f, wB = 0.f;
    float4 zA = {0.f, 0.f, 0.f, 0.f}, zB = {0.f, 0.f, 0.f, 0.f};
    if (aA) { wA = scw[wv][pa]; zA = ((const float4*)(Zk + (size_t)nbr[pa] * SS))[sq]; }
    if (aB) { wB = scw[wv][pb]; zB = ((const float4*)(Zk + (size_t)nbr[pb] * SS))[sq]; }
    o4.x += wA * zA.x + wB * zB.x;
    o4.y += wA * zA.y + wB * zB.y;
    o4.z += wA * zA.z + wB * zB.z;
    o4.w += wA * zA.w + wB * zB.w;
  }
#pragma unroll
  for (int off = 8; off <= 32; off <<= 1) {
    o4.x += __shfl_xor(o4.x, off);
    o4.y += __shfl_xor(o4.y, off);
    o4.z += __shfl_xor(o4.z, off);
    o4.w += __shfl_xor(o4.w, off);
  }
  if (p_sub == 0) {
    float4 o;
    o.x = o4.x * invl; o.y = o4.y * invl; o.z = o4.z * invl; o.w = o4.w * invl;
    ((float4*)AO)[(size_t)row * (KK * SS / 4) + k * 8 + sq] = o;  // 128B/wave
  }
}

// ---------------------------------------------------------------------------
// Kernel 3 (epilogue): Hout = softthresh(H + ETA * AO @ Ufl), Ufl[(k,s)][d]=U[k][d][s].
// 4 rows per block, 1024 blocks; d = tid; AO tile staged in LDS.
// ---------------------------------------------------------------------------
__global__ __launch_bounds__(256) void epilogue_kernel(
    const float* __restrict__ H, const float* __restrict__ U,
    const float* __restrict__ thr, const float* __restrict__ AO,
    float* __restrict__ Hout) {
  __shared__ float AOl[4][KK * SS];   // 2 KB
  const int tid = threadIdx.x;
  const int r0 = blockIdx.x * 4;

  const float4* AO4 = (const float4*)(AO + (size_t)r0 * KK * SS);
  float4* AOl4 = (float4*)&AOl[0][0];
  if (tid < 128) AOl4[tid] = AO4[tid];
  __syncthreads();

  const int d = tid;
  float acc[4] = {0.f, 0.f, 0.f, 0.f};
  const float4* U4 = (const float4*)U;
#pragma unroll
  for (int k = 0; k < KK; k++) {
    const int ubase = (k * DD + d) * (SS / 4);
#pragma unroll
    for (int sq = 0; sq < SS / 4; sq++) {
      const float4 u = U4[ubase + sq];   // thread's 128B row of U[k][d][:]
#pragma unroll
      for (int r = 0; r < 4; r++) {
        const float4 a = AOl4[r * (KK * SS / 4) + k * (SS / 4) + sq];  // LDS b128
        acc[r] += u.x * a.x + u.y * a.y + u.z * a.z + u.w * a.w;
      }
    }
  }
  const float tv = thr[d];
#pragma unroll
  for (int r = 0; r < 4; r++) {
    const float h = H[(size_t)(r0 + r) * DD + d] + ETA * acc[r];
    const float ab = fabsf(h) - tv;
    Hout[(size_t)(r0 + r) * DD + d] = (ab > 0.0f) ? copysignf(ab, h) : 0.0f;
  }
}

// ---------------------------------------------------------------------------
extern "C" void kernel_launch(void* const* d_in, const int* in_sizes, int n_in,
                              void* d_out, int out_size, void* d_ws, size_t ws_size,
                              hipStream_t stream) {
  const float* H    = (const float*)d_in[0];
  const float* mask = (const float*)d_in[1];
  const float* U    = (const float*)d_in[2];
  const float* lp   = (const float*)d_in[3];
  const float* thr  = (const float*)d_in[4];

  float* Hout = (float*)d_out;
  float* loss = Hout + (size_t)NN * DD;      // outputs: [N*D] + [1]

  float* Z     = (float*)d_ws;               // [K][N][S]   2 MB (16B aligned)
  float* AO    = Z + (size_t)KK * NN * SS;   // [N][K*S]    2 MB (16B aligned)
  float* elp   = AO + (size_t)NN * KK * SS;  // [K*S]       (16B aligned)
  float* lossp = elp + KK * SS;              // [10]

  prep_kernel<<<1034, 256, 0, stream>>>(H, U, lp, Z, elp, lossp);
  attn_row<<<NN, 256, 0, stream>>>(mask, Z, elp, lossp, AO, loss);
  epilogue_kernel<<<NN / 4, 256, 0, stream>>>(H, U, thr, AO, Hout);
}